// Round 9
// baseline (348.592 us; speedup 1.0000x reference)
//
#include <hip/hip_runtime.h>
#include <hip/hip_bf16.h>

// LSTM B=8192,T=512,I=3,H=25 + linear[H->1], bf16 MFMA 16x16x32.
// R9: R5-R8 all stuck at ~550-600 cy/tile-step, 55% stall: barrier'd waves
// phase-lock and each lane had only 1-2 independent act chains. Fix: 256
// blocks x 4 waves, 2 tiles/block, the 14 (frag,tile) units spread over 4
// waves: wave w<3 owns frags {2w,2w+1} for BOTH tiles (4 act chains/lane,
// ILP=4), wave 3 owns frag 6 for both tiles. Exactly 1 wave on every SIMD
// (1024 waves), one barrier/iter over just 4 waves. bfrag reads shared:
// 2 ds_read_b128 serve 4 MFMAs.
// x pre-packed bf16 in LDS, 2 chunks of 256 steps (64 KB, 1 mid-loop restage).

#define TSTEPS 512
#define ISZ 3
#define HSZ 25
#define NW 4
#define CHUNK 256
#define TSTRIDE 40          // shorts per batch row (80 B)

typedef __attribute__((ext_vector_type(8))) short bf16x8;
typedef __attribute__((ext_vector_type(4))) float f32x4;

__device__ __forceinline__ unsigned short bf16_bits(float v) {
    return __builtin_bit_cast(unsigned short, __float2bfloat16(v));
}
__device__ __forceinline__ unsigned int pack_bf16(float lo, float hi) {
    return ((unsigned int)bf16_bits(hi) << 16) | (unsigned int)bf16_bits(lo);
}

// 8-trans LSTM cell: c' = sig(a1)*c + sig(a0)*tanh(a2); h = sig(a3)*tanh(c')
__device__ __forceinline__ void lstm_act(const f32x4 acc, float& c, float& h) {
    const float K1 = 1.442695040888963f;   // log2 e
    const float K2 = 2.885390081777927f;   // 2 log2 e
    const float e0 = __builtin_amdgcn_exp2f(-K1 * acc[0]);
    const float e1 = __builtin_amdgcn_exp2f(-K1 * acc[1]);
    const float e2 = __builtin_amdgcn_exp2f(fminf(-K2 * acc[2], 126.0f));
    const float e3 = __builtin_amdgcn_exp2f(-K1 * acc[3]);
    const float f  = __builtin_amdgcn_rcpf(1.0f + e1);
    const float ig = (1.0f - e2) * __builtin_amdgcn_rcpf((1.0f + e0) * (1.0f + e2));
    c = fmaf(f, c, ig);
    const float ec = __builtin_amdgcn_exp2f(fminf(-K2 * c, 126.0f));
    h = (1.0f - ec) * __builtin_amdgcn_rcpf((1.0f + e3) * (1.0f + ec));
}

__global__ __launch_bounds__(NW * 64) void lstm_mfma(
    const float* __restrict__ x,      // [B, T, I]
    const float* __restrict__ w_ih,   // [4H, I]
    const float* __restrict__ w_hh,   // [4H, H]
    const float* __restrict__ b_ih,   // [4H]
    const float* __restrict__ b_hh,   // [4H]
    const float* __restrict__ w_lin,  // [1, H]
    const float* __restrict__ b_lin,  // [1]
    float* __restrict__ out)          // [B, 1]
{
    __shared__ uint2 xpk[2][CHUNK][16];       // 64 KB packed bf16 x (+1.0)
    __shared__ short hb[2][2][16 * TSTRIDE];  // [parity][tile] h rows, 5 KB
    __shared__ float outred[2][NW][16];

    const int tid  = threadIdx.x;
    const int w    = tid >> 6;       // wave 0..3
    const int lane = tid & 63;
    const int n    = lane & 15;      // batch within tile
    const int q    = lane >> 4;      // quad
    const bool isq0 = (q == 0);

    // frag assignment: wave w<3 -> frags 2w, 2w+1 (both tiles); wave 3 -> frag 6
    const int f0 = (w < 3) ? 2 * w : 6;
    const int f1 = (w < 3) ? 2 * w + 1 : 6;     // dup for w=3, masked off
    const bool use1 = (w < 3);
    const int u0 = 4 * f0 + q;                  // unit of frag f0 in this lane
    const int u1 = 4 * f1 + q;                  // (valid only if use1; u1<=23)
    const bool m0 = (u0 < HSZ);                 // f0=6 -> only q==0

    // zero both h parity buffers, both tiles (pad slots stay 0 forever)
    for (int i = tid; i < 2 * 2 * 16 * TSTRIDE; i += NW * 64) ((short*)hb)[i] = 0;

    // ---- stage one 256-step chunk of x for both tiles (pre-packed bf16) ----
    auto stage = [&](int c0) {
        const int bsel = tid & 31;                 // batch in the 32-batch pair
        const int tile = bsel >> 4, nn = bsel & 15;
        const float* __restrict__ g =
            x + (size_t)(blockIdx.x * 32 + bsel) * (TSTEPS * ISZ) + c0 * ISZ;
        for (int tg = tid >> 5; tg < CHUNK / 4; tg += (NW * 64) / 32) {
            const float4* f4 = (const float4*)(g + tg * 12);
            float4 a = f4[0], b4 = f4[1], c4 = f4[2];
            const float s[4][3] = { {a.x, a.y, a.z}, {a.w, b4.x, b4.y},
                                    {b4.z, b4.w, c4.x}, {c4.y, c4.z, c4.w} };
            #pragma unroll
            for (int uu = 0; uu < 4; ++uu) {
                uint2 d;
                d.x = pack_bf16(s[uu][0], s[uu][1]);
                d.y = pack_bf16(s[uu][2], 1.0f);
                xpk[tile][tg * 4 + uu][nn] = d;
            }
        }
    };
    stage(0);

    // ---- A fragments for f0, f1 (loaded once, register-resident) ----
    // A[r=16T+n][k=q*8+j]; row r=4u'+g (unit-major); k: [w_ih 0..2, bias 3, w_hh 4..28]
    bf16x8 af0, af1;
    #pragma unroll
    for (int idx = 0; idx < 2; ++idx) {
        const int T = idx ? f1 : f0;
        bf16x8 af;
        #pragma unroll
        for (int j = 0; j < 8; ++j) {
            const int k = q * 8 + j;
            const int r = 16 * T + n;
            const int uu = r >> 2, g = r & 3;
            float v = 0.0f;
            if (uu < HSZ) {
                const int orow = g * HSZ + uu;     // original i,f,g,o row order
                if (k < ISZ)            v = w_ih[orow * ISZ + k];
                else if (k == ISZ)      v = b_ih[orow] + b_hh[orow];
                else if (k < 4 + HSZ)   v = w_hh[orow * HSZ + (k - 4)];
            }
            af[j] = (short)bf16_bits(v);
        }
        if (idx) af1 = af; else af0 = af;
    }

    __syncthreads();

    // state: c/h for (frag,tile): 00=(f0,A) 01=(f1,A) 10=(f0,B) 11=(f1,B)
    float c00 = 0.f, c01 = 0.f, c10 = 0.f, c11 = 0.f;
    float h00 = 0.f, h01 = 0.f, h10 = 0.f, h11 = 0.f;

    #pragma unroll 1
    for (int t = 0; t < TSTEPS; ++t) {
        if (t == CHUNK) {                 // entry synced by barrier of t-1
            stage(CHUNK);
            __syncthreads();
        }
        const int ts = t & (CHUNK - 1);
        const uint2 xA = xpk[0][ts][n];
        const uint2 xB = xpk[1][ts][n];
        // both tiles' h(t) visible since barrier(t-1)
        bf16x8 bfA = *reinterpret_cast<const bf16x8*>(&hb[t & 1][0][n * TSTRIDE + q * 8]);
        bf16x8 bfB = *reinterpret_cast<const bf16x8*>(&hb[t & 1][1][n * TSTRIDE + q * 8]);

        uint4 biA = __builtin_bit_cast(uint4, bfA);
        uint4 biB = __builtin_bit_cast(uint4, bfB);
        if (isq0) {
            biA.x = xA.x; biA.y = xA.y;
            biB.x = xB.x; biB.y = xB.y;
        }
        const bf16x8 bA = __builtin_bit_cast(bf16x8, biA);
        const bf16x8 bB = __builtin_bit_cast(bf16x8, biB);

        // 2 bfrag reads serve 4 MFMAs; 4 independent act chains follow
        const f32x4 a00 = __builtin_amdgcn_mfma_f32_16x16x32_bf16(
            af0, bA, (f32x4){0.f, 0.f, 0.f, 0.f}, 0, 0, 0);
        const f32x4 a10 = __builtin_amdgcn_mfma_f32_16x16x32_bf16(
            af0, bB, (f32x4){0.f, 0.f, 0.f, 0.f}, 0, 0, 0);
        f32x4 a01, a11;
        if (use1) {
            a01 = __builtin_amdgcn_mfma_f32_16x16x32_bf16(
                af1, bA, (f32x4){0.f, 0.f, 0.f, 0.f}, 0, 0, 0);
            a11 = __builtin_amdgcn_mfma_f32_16x16x32_bf16(
                af1, bB, (f32x4){0.f, 0.f, 0.f, 0.f}, 0, 0, 0);
        }

        lstm_act(a00, c00, h00);
        lstm_act(a10, c10, h10);
        if (use1) {
            lstm_act(a01, c01, h01);
            lstm_act(a11, c11, h11);
        }

        short* const wrA = &hb[(t + 1) & 1][0][n * TSTRIDE + 4];
        short* const wrB = &hb[(t + 1) & 1][1][n * TSTRIDE + 4];
        if (m0) {
            wrA[u0] = (short)bf16_bits(h00);
            wrB[u0] = (short)bf16_bits(h10);
        }
        if (use1) {
            wrA[u1] = (short)bf16_bits(h01);
            wrB[u1] = (short)bf16_bits(h11);
        }
        __syncthreads();                  // ONE barrier per step, both tiles
    }

    // ---- final linear: out[b] = sum_u w_lin[u]*h[u] + b_lin ----
    float vA = 0.f, vB = 0.f;
    if (m0) { vA = w_lin[u0] * h00; vB = w_lin[u0] * h10; }
    if (use1) {
        vA = fmaf(w_lin[u1], h01, vA);
        vB = fmaf(w_lin[u1], h11, vB);
    }
    vA += __shfl_xor(vA, 16); vA += __shfl_xor(vA, 32);
    vB += __shfl_xor(vB, 16); vB += __shfl_xor(vB, 32);
    if (lane < 16) { outred[0][w][lane] = vA; outred[1][w][lane] = vB; }
    __syncthreads();
    if (tid < 32) {
        const int tile = tid >> 4, nn = tid & 15;
        float s = b_lin[0];
        #pragma unroll
        for (int k = 0; k < NW; ++k) s += outred[tile][k][nn];
        out[blockIdx.x * 32 + tile * 16 + nn] = s;
    }
}

extern "C" void kernel_launch(void* const* d_in, const int* in_sizes, int n_in,
                              void* d_out, int out_size, void* d_ws, size_t ws_size,
                              hipStream_t stream) {
    const float* x     = (const float*)d_in[0];
    const float* w_ih  = (const float*)d_in[1];
    const float* w_hh  = (const float*)d_in[2];
    const float* b_ih  = (const float*)d_in[3];
    const float* b_hh  = (const float*)d_in[4];
    const float* w_lin = (const float*)d_in[5];
    const float* b_lin = (const float*)d_in[6];
    float* out = (float*)d_out;

    lstm_mfma<<<8192 / 32, NW * 64, 0, stream>>>(x, w_ih, w_hh, b_ih, b_hh,
                                                 w_lin, b_lin, out);
}